// Round 7
// baseline (154.857 us; speedup 1.0000x reference)
//
#include <hip/hip_runtime.h>

typedef short s16x8 __attribute__((ext_vector_type(8)));
typedef float f32x4 __attribute__((ext_vector_type(4)));

union U16x4 { uint4 u; s16x8 s; };

__device__ inline unsigned short bf16_rn(float f) {
  unsigned int u = __float_as_uint(f);
  return (unsigned short)((u + 0x7FFFu + ((u >> 16) & 1u)) >> 16);
}
__device__ inline float bf16f(unsigned short h) {
  return __uint_as_float(((unsigned int)h) << 16);
}
__device__ inline unsigned int umn(unsigned int a, unsigned int b) { return a < b ? a : b; }
__device__ inline unsigned int umx(unsigned int a, unsigned int b) { return a > b ? a : b; }

// ---------------------------------------------------------------------------
// Kernel 1: biased codebook norms. 16 lanes per code. cbn[k] = 256 + ||e||^2
// (bias > max dist contribution keeps all packed distances positive).
// ---------------------------------------------------------------------------
__global__ __launch_bounds__(256) void vq_norms(const float* __restrict__ cb,
                                                float* __restrict__ cbn) {
  int id = blockIdx.x * 256 + threadIdx.x;
  int k = id >> 4, l = id & 15;
  const float* p = cb + (size_t)k * 128 + l * 8;
  float4 a = *(const float4*)p, b = *(const float4*)(p + 4);
  float s = a.x * a.x + a.y * a.y + a.z * a.z + a.w * a.w +
            b.x * b.x + b.y * b.y + b.z * b.z + b.w * b.w;
#pragma unroll
  for (int off = 1; off < 16; off <<= 1) s += __shfl_xor(s, off);
  if (l == 0) cbn[k] = 256.f + s;
}

// ---------------------------------------------------------------------------
// Kernel 2: codebook -> FRAGMENT-MAJOR hi/lo bf16 image. For tile t (32
// codes), frag (ks, part, c): lane l's 16-B MFMA B-operand slice sits at
// byte offset  t*16384 + (ks*4 + part*2 + c)*1024 + l*16  — so the main
// kernel's B loads are single fully-coalesced 1-KB wave instructions.
// Content for lane l=(i0,q): code = t*32 + c*16 + i0, dims (ks*4+q)*8 .. +8.
// ---------------------------------------------------------------------------
__global__ __launch_bounds__(256) void vq_fragimg(const float* __restrict__ cb,
                                                  unsigned short* __restrict__ img) {
  int gid = blockIdx.x * 256 + threadIdx.x;  // 0..32767
  int l = gid & 63;
  int c = (gid >> 6) & 1;
  int part = (gid >> 7) & 1;
  int ks = (gid >> 8) & 3;
  int tile = gid >> 10;
  int i0 = l & 15, q = l >> 4;
  int code = tile * 32 + c * 16 + i0;
  const float* p = cb + (size_t)code * 128 + (ks * 4 + q) * 8;
  float4 a = *(const float4*)p, b = *(const float4*)(p + 4);
  float v[8] = {a.x, a.y, a.z, a.w, b.x, b.y, b.z, b.w};
  unsigned int w[4];
#pragma unroll
  for (int i = 0; i < 4; ++i) {
    unsigned short o0, o1;
    if (part == 0) {
      o0 = bf16_rn(v[2 * i]);
      o1 = bf16_rn(v[2 * i + 1]);
    } else {
      unsigned short h0 = bf16_rn(v[2 * i]), h1 = bf16_rn(v[2 * i + 1]);
      o0 = bf16_rn(v[2 * i] - bf16f(h0));
      o1 = bf16_rn(v[2 * i + 1] - bf16f(h1));
    }
    w[i] = (unsigned)o0 | ((unsigned)o1 << 16);
  }
  *(uint4*)(img + (size_t)gid * 8) = make_uint4(w[0], w[1], w[2], w[3]);
}

// ---------------------------------------------------------------------------
// Kernel 3: main. Grid 1024 = 512 token-groups x 2 K-halves; 4 waves/block;
// wave owns 32 tokens (A hi/lo in regs). NO LDS, NO barriers: B-frags load
// coalesced from the L2-resident frag-major image, straight into MFMA.
// Packed-uint top-2 (5 id bits stolen from mantissa; bucket ~2e-3), float
// butterfly merge, cand out. 3-pass split-bf16 MFMA as before.
// ---------------------------------------------------------------------------
__global__ __launch_bounds__(256) void vq_main(
    const float* __restrict__ xg, const uint4* __restrict__ img,
    const float* __restrict__ cbn, uint4* __restrict__ cand) {
  const int tid = threadIdx.x;
  const int wave = tid >> 6, lane = tid & 63;
  const int i0 = lane & 15, q = lane >> 4;
  const int half = blockIdx.x & 1;
  const int grp = blockIdx.x >> 1;
  const int tok0 = grp * 128 + wave * 32;

  // ---- load own 32 tokens, split fp32 -> bf16 hi + lo in-register ----
  s16x8 ahi[2][4], alo[2][4];
#pragma unroll
  for (int r = 0; r < 2; ++r)
#pragma unroll
    for (int kf = 0; kf < 4; ++kf) {
      const float* p = xg + (size_t)(tok0 + r * 16 + i0) * 128 + kf * 32 + q * 8;
      float4 a = *(const float4*)p, b = *(const float4*)(p + 4);
      float v[8] = {a.x, a.y, a.z, a.w, b.x, b.y, b.z, b.w};
      s16x8 h, l;
#pragma unroll
      for (int j = 0; j < 8; ++j) {
        unsigned short hh = bf16_rn(v[j]);
        float rr = v[j] - bf16f(hh);
        h[j] = (short)hh;
        l[j] = (short)bf16_rn(rr);
      }
      ahi[r][kf] = h;
      alo[r][kf] = l;
    }

  unsigned int b1[2][4], b2[2][4];
#pragma unroll
  for (int r = 0; r < 2; ++r)
#pragma unroll
    for (int g = 0; g < 4; ++g) { b1[r][g] = 0xFFFFFFFFu; b2[r][g] = 0xFFFFFFFFu; }

  const uint4* gb = img + (size_t)half * 16 * 1024;  // 16 tiles x 1024 uint4
  const float* cnb = cbn + half * 512;

  for (int t = 0; t < 16; ++t) {
    const uint4* tb = gb + t * 1024;
    float cn0 = cnb[t * 32 + i0];
    float cn1 = cnb[t * 32 + 16 + i0];
    f32x4 acc[2][2];
#pragma unroll
    for (int r = 0; r < 2; ++r)
#pragma unroll
      for (int c = 0; c < 2; ++c) acc[r][c] = (f32x4){0.f, 0.f, 0.f, 0.f};

#pragma unroll
    for (int ks = 0; ks < 4; ++ks) {
      U16x4 bh0, bh1, bl0, bl1;
      bh0.u = tb[(ks * 4 + 0) * 64 + lane];
      bh1.u = tb[(ks * 4 + 1) * 64 + lane];
      bl0.u = tb[(ks * 4 + 2) * 64 + lane];
      bl1.u = tb[(ks * 4 + 3) * 64 + lane];
#pragma unroll
      for (int r = 0; r < 2; ++r) {
        acc[r][0] = __builtin_amdgcn_mfma_f32_16x16x32_bf16(ahi[r][ks], bh0.s, acc[r][0], 0, 0, 0);
        acc[r][0] = __builtin_amdgcn_mfma_f32_16x16x32_bf16(ahi[r][ks], bl0.s, acc[r][0], 0, 0, 0);
        acc[r][0] = __builtin_amdgcn_mfma_f32_16x16x32_bf16(alo[r][ks], bh0.s, acc[r][0], 0, 0, 0);
        acc[r][1] = __builtin_amdgcn_mfma_f32_16x16x32_bf16(ahi[r][ks], bh1.s, acc[r][1], 0, 0, 0);
        acc[r][1] = __builtin_amdgcn_mfma_f32_16x16x32_bf16(ahi[r][ks], bl1.s, acc[r][1], 0, 0, 0);
        acc[r][1] = __builtin_amdgcn_mfma_f32_16x16x32_bf16(alo[r][ks], bh1.s, acc[r][1], 0, 0, 0);
      }
    }
    // ---- packed top-2: u = (bits(dd) & ~31) | (t*2+c); dd > 0 via +256 bias.
    // id ascending == k ascending within a stream -> first-min semantics.
#pragma unroll
    for (int c = 0; c < 2; ++c) {
      float cn = c ? cn1 : cn0;
      unsigned int sid = (unsigned)(t * 2 + c);
#pragma unroll
      for (int r = 0; r < 2; ++r)
#pragma unroll
        for (int g = 0; g < 4; ++g) {
          float dd = fmaf(-2.f, acc[r][c][g], cn);
          unsigned int u = (__float_as_uint(dd) & 0xFFFFFFE0u) | sid;
          unsigned int m = umx(b1[r][g], u);
          b1[r][g] = umn(b1[r][g], u);
          b2[r][g] = umn(b2[r][g], m);
        }
    }
  }

  // ---- unpack to (bucketed d, global k), butterfly-merge over i0 lanes ----
  float d1[2][4], d2[2][4];
  int k1[2][4], k2[2][4];
#pragma unroll
  for (int r = 0; r < 2; ++r)
#pragma unroll
    for (int g = 0; g < 4; ++g) {
      unsigned int v1 = b1[r][g], v2 = b2[r][g];
      d1[r][g] = __uint_as_float(v1 & 0xFFFFFFE0u);
      d2[r][g] = __uint_as_float(v2 & 0xFFFFFFE0u);
      int id1 = (int)(v1 & 31u), id2 = (int)(v2 & 31u);
      k1[r][g] = half * 512 + (id1 >> 1) * 32 + (id1 & 1) * 16 + i0;
      k2[r][g] = half * 512 + (id2 >> 1) * 32 + (id2 & 1) * 16 + i0;
    }
#pragma unroll
  for (int off = 1; off < 16; off <<= 1) {
#pragma unroll
    for (int r = 0; r < 2; ++r)
#pragma unroll
      for (int g = 0; g < 4; ++g) {
        float od1 = __shfl_xor(d1[r][g], off);
        int ok1 = __shfl_xor(k1[r][g], off);
        float od2 = __shfl_xor(d2[r][g], off);
        int ok2 = __shfl_xor(k2[r][g], off);
        bool t1 = (od1 < d1[r][g]) || (od1 == d1[r][g] && ok1 < k1[r][g]);
        float w1d = t1 ? od1 : d1[r][g];
        int w1k = t1 ? ok1 : k1[r][g];
        float l1d = t1 ? d1[r][g] : od1;
        int l1k = t1 ? k1[r][g] : ok1;
        float c2d = t1 ? od2 : d2[r][g];
        int c2k = t1 ? ok2 : k2[r][g];
        bool t2 = (l1d < c2d) || (l1d == c2d && l1k < c2k);
        d1[r][g] = w1d; k1[r][g] = w1k;
        d2[r][g] = t2 ? l1d : c2d;
        k2[r][g] = t2 ? l1k : c2k;
      }
  }
  if (i0 == 0) {
#pragma unroll
    for (int r = 0; r < 2; ++r)
#pragma unroll
      for (int g = 0; g < 4; ++g) {
        int token = tok0 + r * 16 + q * 4 + g;  // C-layout row = q*4+g
        cand[(size_t)half * 65536 + token] =
            make_uint4(__float_as_uint(d1[r][g]), (unsigned)k1[r][g],
                       __float_as_uint(d2[r][g]), (unsigned)k2[r][g]);
      }
  }
}

// ---------------------------------------------------------------------------
// Kernel 4: merge halves. Approx-top-2 of 4 candidates, exact fp32 rescore,
// xq write, direct loss store. Block = 128 tokens = 1 loss slot.
// ---------------------------------------------------------------------------
__global__ __launch_bounds__(256) void vq_merge(
    const float* __restrict__ xg, const float* __restrict__ cb,
    const uint4* __restrict__ cand, float* __restrict__ xq,
    float* __restrict__ loss) {
  __shared__ float sW[4];
  const int tid = threadIdx.x;
  const int l = tid & 15;
  float lacc = 0.f;
#pragma unroll
  for (int p = 0; p < 8; ++p) {
    int token = blockIdx.x * 128 + p * 16 + (tid >> 4);
    uint4 A = cand[token], B = cand[65536 + token];
    float a1 = __uint_as_float(A.x), a2 = __uint_as_float(A.z);
    float b1 = __uint_as_float(B.x), b2 = __uint_as_float(B.z);
    int ja1 = (int)A.y, ja2 = (int)A.w, jb1 = (int)B.y, jb2 = (int)B.w;
    bool afirst = (a1 < b1) || (a1 == b1 && ja1 < jb1);
    int ka = afirst ? ja1 : jb1;
    float sd = afirst ? a2 : b2;
    int sk = afirst ? ja2 : jb2;
    float od = afirst ? b1 : a1;
    int ok = afirst ? jb1 : ja1;
    bool so_ = (od < sd) || (od == sd && ok < sk);
    int kb = so_ ? ok : sk;

    const float* xp = xg + (size_t)token * 128 + l * 8;
    float4 xa = *(const float4*)xp, xb = *(const float4*)(xp + 4);
    const float* p1 = cb + (size_t)ka * 128 + l * 8;
    float4 ua = *(const float4*)p1, ub = *(const float4*)(p1 + 4);
    const float* p2 = cb + (size_t)kb * 128 + l * 8;
    float4 va = *(const float4*)p2, vb = *(const float4*)(p2 + 4);
    float xv[8] = {xa.x, xa.y, xa.z, xa.w, xb.x, xb.y, xb.z, xb.w};
    float e1[8] = {ua.x, ua.y, ua.z, ua.w, ub.x, ub.y, ub.z, ub.w};
    float e2[8] = {va.x, va.y, va.z, va.w, vb.x, vb.y, vb.z, vb.w};
    float s1 = 0.f, s2 = 0.f;
#pragma unroll
    for (int j = 0; j < 8; ++j) {
      float f1 = xv[j] - e1[j];
      float f2 = xv[j] - e2[j];
      s1 = fmaf(f1, f1, s1);
      s2 = fmaf(f2, f2, s2);
    }
#pragma unroll
    for (int off = 1; off < 16; off <<= 1) {
      s1 += __shfl_xor(s1, off);
      s2 += __shfl_xor(s2, off);
    }
    bool tk = (s2 < s1) || (s2 == s1 && kb < ka);
    float dwin = tk ? s2 : s1;
    float w[8];
#pragma unroll
    for (int j = 0; j < 8; ++j) w[j] = tk ? e2[j] : e1[j];
    float* op = xq + (size_t)token * 128 + l * 8;
    *(float4*)op = make_float4(w[0], w[1], w[2], w[3]);
    *(float4*)(op + 4) = make_float4(w[4], w[5], w[6], w[7]);
    if (l == 0) lacc += dwin;
  }
#pragma unroll
  for (int off = 1; off < 64; off <<= 1) lacc += __shfl_xor(lacc, off);
  if ((tid & 63) == 0) sW[tid >> 6] = lacc;
  __syncthreads();
  if (tid == 0)
    loss[blockIdx.x] = (sW[0] + sW[1] + sW[2] + sW[3]) * (1.25f / 16384.f);
}

// ---------------------------------------------------------------------------
extern "C" void kernel_launch(void* const* d_in, const int* in_sizes, int n_in,
                              void* d_out, int out_size, void* d_ws, size_t ws_size,
                              hipStream_t stream) {
  const float* x = (const float*)d_in[0];   // [8,64,128,128] fp32
  const float* cb = (const float*)d_in[1];  // [1024,128] fp32
  float* out = (float*)d_out;
  float* xq = out;
  float* loss = out + (size_t)8 * 64 * 128 * 128;  // 512 floats

  // ws: cbimg 512 KB | cbn 4 KB | cand 2 MB
  unsigned short* cbimg = (unsigned short*)d_ws;
  float* cbn = (float*)(cbimg + (size_t)1024 * 128 * 2);
  uint4* cand = (uint4*)(cbn + 1024);

  vq_norms<<<64, 256, 0, stream>>>(cb, cbn);
  vq_fragimg<<<128, 256, 0, stream>>>(cb, cbimg);
  vq_main<<<1024, 256, 0, stream>>>(x, (const uint4*)cbimg, cbn, cand);
  vq_merge<<<512, 256, 0, stream>>>(x, cb, cand, xq, loss);
}